// Round 1
// baseline (1580.615 us; speedup 1.0000x reference)
//
#include <hip/hip_runtime.h>
#include <hip/hip_bf16.h>
#include <math.h>

// ---------------------------------------------------------------------------
// Attention forward: out = softmax(rope(x@wq) @ rope(x@wk)^T * scale + causal) @ (x@wv) @ wo
// Outputs (concatenated fp32): out (1,2048,4096), k (1,32,2048,128), v (1,32,2048,128)
// Strategy: bf16 MFMA for all matmuls (fp32 accum), flash-style attention.
// ---------------------------------------------------------------------------

#define L_SEQ 2048
#define DIM   4096
#define NH    32
#define NKV   8
#define HD    128
#define SCALE 0.08838834764831845f   // 128^-0.5

typedef __bf16 bf16x8 __attribute__((ext_vector_type(8)));
typedef __bf16 bf16x4 __attribute__((ext_vector_type(4)));
typedef float  f32x4  __attribute__((ext_vector_type(4)));

// ---------------- cast fp32 -> bf16 (4 elems/thread) ----------------
__global__ void cast_bf16_kernel(const float* __restrict__ in,
                                 __bf16* __restrict__ out, long n4) {
  long i = blockIdx.x * (long)blockDim.x + threadIdx.x;
  if (i >= n4) return;
  float4 f = reinterpret_cast<const float4*>(in)[i];
  bf16x4 o;
  o[0] = (__bf16)f.x; o[1] = (__bf16)f.y; o[2] = (__bf16)f.z; o[3] = (__bf16)f.w;
  reinterpret_cast<bf16x4*>(out)[i] = o;
}

// ---------------- bf16 MFMA GEMM: C[M,N] = A[M,K] * B[K,N] ----------------
// 64x64 block tile, 4 waves of 32x32, BK=64.
// mode 0: fp32 row-major C.  mode 2: bf16 head-major C[(n>>7)][row][n&127].
#define LDT 72   // LDS pitch (bf16 elems), 144B rows -> 16B aligned, 2-way bank alias only

__global__ __launch_bounds__(256) void gemm_bf16(
    const __bf16* __restrict__ A, const __bf16* __restrict__ B,
    void* __restrict__ C, int M, int N, int K, int mode, int Lrows) {
  __shared__ __bf16 As[64 * LDT] __attribute__((aligned(16)));
  __shared__ __bf16 Bs[64 * LDT] __attribute__((aligned(16)));   // transposed: Bs[n][k]
  const int m0 = blockIdx.y * 64, n0 = blockIdx.x * 64;
  const int t = threadIdx.x;
  const int wave = t >> 6, lane = t & 63;
  const int quad = lane >> 4, l16 = lane & 15;
  const int wm = (wave >> 1) * 32, wn = (wave & 1) * 32;
  const int rowA = t >> 3;            // 0..31
  const int octA = (t & 7) * 8;       // 0..56

  f32x4 acc[2][2] = {};

  for (int kt = 0; kt < K; kt += 64) {
    __syncthreads();
    // stage A tile (64 rows x 64 k), vector 16B
#pragma unroll
    for (int it = 0; it < 2; ++it) {
      int r = rowA + it * 32;
      bf16x8 v = *reinterpret_cast<const bf16x8*>(A + (long)(m0 + r) * K + kt + octA);
      *reinterpret_cast<bf16x8*>(&As[r * LDT + octA]) = v;
    }
    // stage B tile transposed: global row-major [k][n] -> LDS [n][k]
#pragma unroll
    for (int it = 0; it < 2; ++it) {
      int kr = rowA + it * 32;
      bf16x8 v = *reinterpret_cast<const bf16x8*>(B + (long)(kt + kr) * N + n0 + octA);
#pragma unroll
      for (int e = 0; e < 8; ++e) Bs[(octA + e) * LDT + kr] = v[e];
    }
    __syncthreads();
#pragma unroll
    for (int ks = 0; ks < 64; ks += 32) {
      bf16x8 a0 = *reinterpret_cast<const bf16x8*>(&As[(wm + l16) * LDT + ks + quad * 8]);
      bf16x8 a1 = *reinterpret_cast<const bf16x8*>(&As[(wm + 16 + l16) * LDT + ks + quad * 8]);
      bf16x8 b0 = *reinterpret_cast<const bf16x8*>(&Bs[(wn + l16) * LDT + ks + quad * 8]);
      bf16x8 b1 = *reinterpret_cast<const bf16x8*>(&Bs[(wn + 16 + l16) * LDT + ks + quad * 8]);
      acc[0][0] = __builtin_amdgcn_mfma_f32_16x16x32_bf16(a0, b0, acc[0][0], 0, 0, 0);
      acc[0][1] = __builtin_amdgcn_mfma_f32_16x16x32_bf16(a0, b1, acc[0][1], 0, 0, 0);
      acc[1][0] = __builtin_amdgcn_mfma_f32_16x16x32_bf16(a1, b0, acc[1][0], 0, 0, 0);
      acc[1][1] = __builtin_amdgcn_mfma_f32_16x16x32_bf16(a1, b1, acc[1][1], 0, 0, 0);
    }
  }
  // epilogue: C/D layout col=lane&15, row=quad*4+reg
#pragma unroll
  for (int tm = 0; tm < 2; ++tm)
#pragma unroll
    for (int tn = 0; tn < 2; ++tn)
#pragma unroll
      for (int r = 0; r < 4; ++r) {
        int row = m0 + wm + tm * 16 + quad * 4 + r;
        int col = n0 + wn + tn * 16 + l16;
        float v = acc[tm][tn][r];
        if (mode == 0) {
          ((float*)C)[(long)row * N + col] = v;
        } else {
          long idx = ((long)(col >> 7) * Lrows + row) * HD + (col & 127);
          ((__bf16*)C)[idx] = (__bf16)v;
        }
      }
}

// ---------------- RoPE (traditional / interleaved), in-place bf16 ----------------
__global__ void rope_q_kernel(__bf16* __restrict__ q /*[NH][L][HD]*/) {
  int idx = blockIdx.x * blockDim.x + threadIdx.x;   // (h,l,i) : 32*2048*64
  int i = idx & 63;
  int l = (idx >> 6) & 2047;
  int h = idx >> 17;
  if (h >= NH) return;
  long base = ((long)h * L_SEQ + l) * HD;
  float x1 = (float)q[base + 2 * i];
  float x2 = (float)q[base + 2 * i + 1];
  float inv = powf(10000.0f, -(float)(2 * i) / 128.0f);
  float ang = (float)l * inv;
  float s, c; sincosf(ang, &s, &c);
  q[base + 2 * i]     = (__bf16)(x1 * c - x2 * s);
  q[base + 2 * i + 1] = (__bf16)(x1 * s + x2 * c);
}

__global__ void rope_k_kernel(__bf16* __restrict__ kb /*[NKV][L][HD]*/,
                              float* __restrict__ kout /*[NH][L][HD]*/) {
  int idx = blockIdx.x * blockDim.x + threadIdx.x;   // (kv,l,i): 8*2048*64
  int i = idx & 63;
  int l = (idx >> 6) & 2047;
  int kv = idx >> 17;
  if (kv >= NKV) return;
  long base = ((long)kv * L_SEQ + l) * HD;
  float x1 = (float)kb[base + 2 * i];
  float x2 = (float)kb[base + 2 * i + 1];
  float inv = powf(10000.0f, -(float)(2 * i) / 128.0f);
  float ang = (float)l * inv;
  float s, c; sincosf(ang, &s, &c);
  float r1 = x1 * c - x2 * s;
  float r2 = x1 * s + x2 * c;
  kb[base + 2 * i]     = (__bf16)r1;
  kb[base + 2 * i + 1] = (__bf16)r2;
#pragma unroll
  for (int rr = 0; rr < 4; ++rr) {
    long ob = ((long)(kv * 4 + rr) * L_SEQ + l) * HD;
    kout[ob + 2 * i]     = r1;
    kout[ob + 2 * i + 1] = r2;
  }
}

__global__ void v_expand_kernel(const __bf16* __restrict__ vb /*[NKV][L][HD]*/,
                                float* __restrict__ vout /*[NH][L][HD]*/) {
  int idx = blockIdx.x * blockDim.x + threadIdx.x;   // (kv,l,d): 8*2048*128
  int d = idx & 127;
  int l = (idx >> 7) & 2047;
  int kv = idx >> 18;
  if (kv >= NKV) return;
  float v = (float)vb[((long)kv * L_SEQ + l) * HD + d];
#pragma unroll
  for (int rr = 0; rr < 4; ++rr)
    vout[((long)(kv * 4 + rr) * L_SEQ + l) * HD + d] = v;
}

// ---------------- flash attention: 1 workgroup = (head, 64-row q block) ----------------
// 4 waves; wave w owns q rows [w*16, w*16+16). Online softmax, causal.
#define QKP 136   // Q/K LDS pitch (272B rows)
#define VPP 72    // V^T / P LDS pitch (144B rows)

__global__ __launch_bounds__(256) void attn_kernel(
    const __bf16* __restrict__ Q, const __bf16* __restrict__ K,
    const __bf16* __restrict__ V, __bf16* __restrict__ O /*[L][NH*HD]*/) {
  __shared__ __bf16 Qs[64 * QKP]  __attribute__((aligned(16)));
  __shared__ __bf16 Ks[64 * QKP]  __attribute__((aligned(16)));
  __shared__ __bf16 Vts[128 * VPP] __attribute__((aligned(16)));  // [d][kv]
  __shared__ __bf16 Ps[64 * VPP]  __attribute__((aligned(16)));   // [m][kv]

  const int qb = blockIdx.x, h = blockIdx.y;
  const int l0 = qb * 64;
  const int t = threadIdx.x, wave = t >> 6, lane = t & 63;
  const int quad = lane >> 4, l16 = lane & 15;
  const int mw = wave * 16;
  const __bf16* Qh = Q + (long)h * L_SEQ * HD;
  const __bf16* Kh = K + (long)(h >> 2) * L_SEQ * HD;
  const __bf16* Vh = V + (long)(h >> 2) * L_SEQ * HD;

  // load Q tile once (64 x 128)
  {
    int r = t >> 4, oct = (t & 15) * 8;
#pragma unroll
    for (int it = 0; it < 4; ++it) {
      int rr = r + it * 16;
      bf16x8 v = *reinterpret_cast<const bf16x8*>(Qh + (long)(l0 + rr) * HD + oct);
      *reinterpret_cast<bf16x8*>(&Qs[rr * QKP + oct]) = v;
    }
  }

  f32x4 o_acc[8] = {};
  float m_run[4], l_run[4];
#pragma unroll
  for (int r = 0; r < 4; ++r) { m_run[r] = -1e30f; l_run[r] = 0.f; }

  for (int j = 0; j <= qb; ++j) {
    __syncthreads();   // prev iter reads done (also covers Qs store on iter 0)
    // stage K block (64x128) and V block transposed (128x64)
    {
      int r = t >> 4, oct = (t & 15) * 8;
#pragma unroll
      for (int it = 0; it < 4; ++it) {
        int rr = r + it * 16;
        bf16x8 kv8 = *reinterpret_cast<const bf16x8*>(Kh + (long)(j * 64 + rr) * HD + oct);
        *reinterpret_cast<bf16x8*>(&Ks[rr * QKP + oct]) = kv8;
        bf16x8 vv = *reinterpret_cast<const bf16x8*>(Vh + (long)(j * 64 + rr) * HD + oct);
#pragma unroll
        for (int e = 0; e < 8; ++e) Vts[(oct + e) * VPP + rr] = vv[e];
      }
    }
    __syncthreads();

    // S strip (16 x 64) = Q_strip * K^T
    f32x4 s[4] = {};
#pragma unroll
    for (int ds = 0; ds < 128; ds += 32) {
      bf16x8 aq = *reinterpret_cast<const bf16x8*>(&Qs[(mw + l16) * QKP + ds + quad * 8]);
#pragma unroll
      for (int tn = 0; tn < 4; ++tn) {
        bf16x8 bk = *reinterpret_cast<const bf16x8*>(&Ks[(tn * 16 + l16) * QKP + ds + quad * 8]);
        s[tn] = __builtin_amdgcn_mfma_f32_16x16x32_bf16(aq, bk, s[tn], 0, 0, 0);
      }
    }
    // scale + causal mask (diag block only)
#pragma unroll
    for (int tn = 0; tn < 4; ++tn)
#pragma unroll
      for (int r = 0; r < 4; ++r) {
        float v = s[tn][r] * SCALE;
        if (j == qb && (tn * 16 + l16) > (mw + quad * 4 + r)) v = -1e30f;
        s[tn][r] = v;
      }
    // online softmax per row (row = mw + quad*4 + r; reduce over 16 lanes of quad)
    float alpha[4];
#pragma unroll
    for (int r = 0; r < 4; ++r) {
      float mx = fmaxf(fmaxf(s[0][r], s[1][r]), fmaxf(s[2][r], s[3][r]));
#pragma unroll
      for (int off = 1; off < 16; off <<= 1) mx = fmaxf(mx, __shfl_xor(mx, off, 64));
      float mnew = fmaxf(m_run[r], mx);
      alpha[r] = __expf(m_run[r] - mnew);
      float rs = 0.f;
#pragma unroll
      for (int tn = 0; tn < 4; ++tn) {
        float p = __expf(s[tn][r] - mnew);
        s[tn][r] = p;
        rs += p;
      }
#pragma unroll
      for (int off = 1; off < 16; off <<= 1) rs += __shfl_xor(rs, off, 64);
      l_run[r] = l_run[r] * alpha[r] + rs;
      m_run[r] = mnew;
    }
    // P (C-layout) -> LDS [m][kv] (per-wave private rows, no barrier needed)
#pragma unroll
    for (int tn = 0; tn < 4; ++tn)
#pragma unroll
      for (int r = 0; r < 4; ++r)
        Ps[(mw + quad * 4 + r) * VPP + tn * 16 + l16] = (__bf16)s[tn][r];
    // rescale O accumulator
#pragma unroll
    for (int td = 0; td < 8; ++td)
#pragma unroll
      for (int r = 0; r < 4; ++r) o_acc[td][r] *= alpha[r];
    // O += P * V   (contract over kv: 2 k-steps of 32)
#pragma unroll
    for (int ks = 0; ks < 64; ks += 32) {
      bf16x8 ap = *reinterpret_cast<const bf16x8*>(&Ps[(mw + l16) * VPP + ks + quad * 8]);
#pragma unroll
      for (int td = 0; td < 8; ++td) {
        bf16x8 bv = *reinterpret_cast<const bf16x8*>(&Vts[(td * 16 + l16) * VPP + ks + quad * 8]);
        o_acc[td] = __builtin_amdgcn_mfma_f32_16x16x32_bf16(ap, bv, o_acc[td], 0, 0, 0);
      }
    }
  }
  // epilogue: normalize, write O row-major [l][h*128+d] (bf16, feeds final GEMM)
#pragma unroll
  for (int td = 0; td < 8; ++td)
#pragma unroll
    for (int r = 0; r < 4; ++r) {
      int row = l0 + mw + quad * 4 + r;
      int col = h * HD + td * 16 + l16;
      O[(long)row * DIM + col] = (__bf16)(o_acc[td][r] / l_run[r]);
    }
}

// ---------------------------------------------------------------------------
extern "C" void kernel_launch(void* const* d_in, const int* in_sizes, int n_in,
                              void* d_out, int out_size, void* d_ws, size_t ws_size,
                              hipStream_t stream) {
  const float* x  = (const float*)d_in[0];
  const float* wq = (const float*)d_in[1];
  const float* wk = (const float*)d_in[2];
  const float* wv = (const float*)d_in[3];
  const float* wo = (const float*)d_in[4];
  // d_in[5] = mask (unused; causal computed in-kernel)

  float* out   = (float*)d_out;                       // 2048*4096
  float* k_out = out + (long)L_SEQ * DIM;             // [32][2048][128]
  float* v_out = k_out + (long)NH * L_SEQ * HD;

  char* ws = (char*)d_ws;
  __bf16* Xb  = (__bf16*)ws; ws += (long)L_SEQ * DIM * 2;
  __bf16* Wqb = (__bf16*)ws; ws += (long)DIM * DIM * 2;
  __bf16* Wkb = (__bf16*)ws; ws += (long)DIM * (NKV * HD) * 2;
  __bf16* Wvb = (__bf16*)ws; ws += (long)DIM * (NKV * HD) * 2;
  __bf16* Wob = (__bf16*)ws; ws += (long)DIM * DIM * 2;
  __bf16* Qh  = (__bf16*)ws; ws += (long)NH * L_SEQ * HD * 2;   // head-major
  __bf16* Kh  = (__bf16*)ws; ws += (long)NKV * L_SEQ * HD * 2;
  __bf16* Vh  = (__bf16*)ws; ws += (long)NKV * L_SEQ * HD * 2;
  __bf16* Ob  = (__bf16*)ws; ws += (long)L_SEQ * DIM * 2;

  // casts (4 elems/thread)
  {
    long n;
    n = (long)L_SEQ * DIM;        cast_bf16_kernel<<<dim3(n / 1024), 256, 0, stream>>>(x,  Xb,  n / 4);
    n = (long)DIM * DIM;          cast_bf16_kernel<<<dim3(n / 1024), 256, 0, stream>>>(wq, Wqb, n / 4);
    n = (long)DIM * NKV * HD;     cast_bf16_kernel<<<dim3(n / 1024), 256, 0, stream>>>(wk, Wkb, n / 4);
    n = (long)DIM * NKV * HD;     cast_bf16_kernel<<<dim3(n / 1024), 256, 0, stream>>>(wv, Wvb, n / 4);
    n = (long)DIM * DIM;          cast_bf16_kernel<<<dim3(n / 1024), 256, 0, stream>>>(wo, Wob, n / 4);
  }
  // QKV projections (bf16 head-major output)
  gemm_bf16<<<dim3(DIM / 64, L_SEQ / 64), 256, 0, stream>>>(Xb, Wqb, Qh, L_SEQ, DIM, DIM, 2, L_SEQ);
  gemm_bf16<<<dim3((NKV * HD) / 64, L_SEQ / 64), 256, 0, stream>>>(Xb, Wkb, Kh, L_SEQ, NKV * HD, DIM, 2, L_SEQ);
  gemm_bf16<<<dim3((NKV * HD) / 64, L_SEQ / 64), 256, 0, stream>>>(Xb, Wvb, Vh, L_SEQ, NKV * HD, DIM, 2, L_SEQ);
  // RoPE (in-place) + fp32 k/v outputs with GQA repeat
  rope_q_kernel<<<dim3((NH * L_SEQ * 64) / 256), 256, 0, stream>>>(Qh);
  rope_k_kernel<<<dim3((NKV * L_SEQ * 64) / 256), 256, 0, stream>>>(Kh, k_out);
  v_expand_kernel<<<dim3((NKV * L_SEQ * HD) / 256), 256, 0, stream>>>(Vh, v_out);
  // flash attention
  attn_kernel<<<dim3(L_SEQ / 64, NH), 256, 0, stream>>>(Qh, Kh, Vh, Ob);
  // output projection (fp32 row-major to d_out)
  gemm_bf16<<<dim3(DIM / 64, L_SEQ / 64), 256, 0, stream>>>(Ob, Wob, out, L_SEQ, DIM, DIM, 0, L_SEQ);
}

// Round 2
// 673.370 us; speedup vs baseline: 2.3473x; 2.3473x over previous
//
#include <hip/hip_runtime.h>
#include <hip/hip_bf16.h>
#include <math.h>

// ---------------------------------------------------------------------------
// GQA attention fwd. bf16 MFMA everywhere, fp32 accum.
// Round 2: S^T trick (K·Q^T) for cheap softmax, global V-transpose,
// global_load_lds(16B) + XOR-swizzled LDS staging, 128x128 m97-style GEMMs.
// ---------------------------------------------------------------------------

#define L_SEQ 2048
#define DIM   4096
#define NH    32
#define NKV   8
#define HD    128
#define SCALE 0.08838834764831845f   // 128^-0.5

typedef __bf16 bf16x8 __attribute__((ext_vector_type(8)));
typedef __bf16 bf16x4 __attribute__((ext_vector_type(4)));
typedef __bf16 bf16x2 __attribute__((ext_vector_type(2)));
typedef float  f32x4  __attribute__((ext_vector_type(4)));

// async global->LDS, 16B per lane. LDS dst = uniform base + lane*16.
__device__ __forceinline__ void gld16(const void* g, void* l) {
  __builtin_amdgcn_global_load_lds(
      (const __attribute__((address_space(1))) void*)g,
      (__attribute__((address_space(3))) void*)l, 16, 0, 0);
}

// ---------------- plain cast fp32 -> bf16 ----------------
__global__ void cast_bf16_kernel(const float* __restrict__ in,
                                 __bf16* __restrict__ out, long n4) {
  long i = blockIdx.x * (long)blockDim.x + threadIdx.x;
  if (i >= n4) return;
  float4 f = reinterpret_cast<const float4*>(in)[i];
  bf16x4 o;
  o[0] = (__bf16)f.x; o[1] = (__bf16)f.y; o[2] = (__bf16)f.z; o[3] = (__bf16)f.w;
  reinterpret_cast<bf16x4*>(out)[i] = o;
}

// ---------------- transpose-cast: in[K][N] f32 -> out[N][K] bf16 ----------------
__global__ void tcast_kernel(const float* __restrict__ in, __bf16* __restrict__ out,
                             int K, int N) {
  __shared__ float tile[32][33];
  int n0 = blockIdx.x * 32, k0 = blockIdx.y * 32;
  int tx = threadIdx.x & 31, ty = threadIdx.x >> 5;   // 256 thr: ty 0..7
#pragma unroll
  for (int i = 0; i < 4; ++i)
    tile[ty + i * 8][tx] = in[(long)(k0 + ty + i * 8) * N + n0 + tx];
  __syncthreads();
#pragma unroll
  for (int i = 0; i < 4; ++i)
    out[(long)(n0 + ty + i * 8) * K + k0 + tx] = (__bf16)tile[tx][ty + i * 8];
}

// ---------------- 128x128 GEMM, C = A[M][K] * Bt[N][K]^T ----------------
// global_load_lds staging, XOR-swizzled chunks (16B), BK=64, 4 waves x 64x64.
// mode 0: fp32 row-major C. mode 2: bf16 head-major C[(col>>7)][row][col&127].
// blockIdx.z selects (B0,C0) / (B1,C1) so K+V projections fuse in one launch.
__global__ __launch_bounds__(256) void gemm128(
    const __bf16* __restrict__ A, const __bf16* __restrict__ B0,
    const __bf16* __restrict__ B1, void* __restrict__ C0, void* __restrict__ C1,
    int M, int N, int K, int mode) {
  __shared__ __bf16 As[128 * 64] __attribute__((aligned(16)));
  __shared__ __bf16 Bs[128 * 64] __attribute__((aligned(16)));
  const __bf16* Bt = blockIdx.z ? B1 : B0;
  void* C = blockIdx.z ? C1 : C0;
  const int m0 = blockIdx.y * 128, n0 = blockIdx.x * 128;
  const int t = threadIdx.x, wave = t >> 6, lane = t & 63;
  const int quad = lane >> 4, l16 = lane & 15;
  const int wm = (wave >> 1) * 64, wn = (wave & 1) * 64;

  // staging map: chunk c -> row r=c>>3, phys chunk pc=c&7 holds logical kc=pc^(r&7)
  int ar[4], ak[4];
#pragma unroll
  for (int it = 0; it < 4; ++it) {
    int c = it * 256 + t;
    ar[it] = c >> 3;
    ak[it] = ((c & 7) ^ (ar[it] & 7)) * 8;   // k elem offset
  }

  f32x4 acc[4][4] = {};

  for (int kt = 0; kt < K; kt += 64) {
    __syncthreads();
#pragma unroll
    for (int it = 0; it < 4; ++it) {
      gld16(A  + (long)(m0 + ar[it]) * K + kt + ak[it],
            (char*)As + (size_t)(it * 256 + wave * 64) * 16);
      gld16(Bt + (long)(n0 + ar[it]) * K + kt + ak[it],
            (char*)Bs + (size_t)(it * 256 + wave * 64) * 16);
    }
    __syncthreads();
#pragma unroll
    for (int ks = 0; ks < 2; ++ks) {
      bf16x8 af[4], bfr[4];
      const int sw = ((ks * 4 + quad) ^ (l16 & 7)) * 16;
#pragma unroll
      for (int i = 0; i < 4; ++i) {
        af[i]  = *(const bf16x8*)((char*)As + (wm + i * 16 + l16) * 128 + sw);
        bfr[i] = *(const bf16x8*)((char*)Bs + (wn + i * 16 + l16) * 128 + sw);
      }
#pragma unroll
      for (int tm = 0; tm < 4; ++tm)
#pragma unroll
        for (int tn = 0; tn < 4; ++tn)
          acc[tm][tn] = __builtin_amdgcn_mfma_f32_16x16x32_bf16(
              af[tm], bfr[tn], acc[tm][tn], 0, 0, 0);
    }
  }
  // epilogue: C/D layout col=lane&15, row=quad*4+reg
#pragma unroll
  for (int tm = 0; tm < 4; ++tm)
#pragma unroll
    for (int tn = 0; tn < 4; ++tn)
#pragma unroll
      for (int r = 0; r < 4; ++r) {
        int row = m0 + wm + tm * 16 + quad * 4 + r;
        int col = n0 + wn + tn * 16 + l16;
        float v = acc[tm][tn][r];
        if (mode == 0) {
          ((float*)C)[(long)row * N + col] = v;
        } else {
          long idx = ((long)(col >> 7) * L_SEQ + row) * HD + (col & 127);
          ((__bf16*)C)[idx] = (__bf16)v;
        }
      }
}

// ---------------- RoPE (traditional / interleaved) ----------------
#define NLOG2_10K 13.287712379549449f   // log2(10000)

__global__ void rope_q_kernel(__bf16* __restrict__ q /*[NH][L][HD]*/) {
  int idx = blockIdx.x * blockDim.x + threadIdx.x;   // (h,l,i) : 32*2048*64
  int i = idx & 63, l = (idx >> 6) & 2047, h = idx >> 17;
  if (h >= NH) return;
  long base = ((long)h * L_SEQ + l) * HD + 2 * i;
  bf16x2 x12 = *(bf16x2*)(q + base);
  float x1 = (float)x12[0], x2 = (float)x12[1];
  float inv = exp2f((float)i * (-NLOG2_10K / 64.0f));
  float s, c; __sincosf((float)l * inv, &s, &c);
  bf16x2 o; o[0] = (__bf16)(x1 * c - x2 * s); o[1] = (__bf16)(x1 * s + x2 * c);
  *(bf16x2*)(q + base) = o;
}

__global__ void rope_k_kernel(__bf16* __restrict__ kb /*[NKV][L][HD]*/,
                              float* __restrict__ kout /*[NH][L][HD]*/) {
  int idx = blockIdx.x * blockDim.x + threadIdx.x;   // (kv,l,i): 8*2048*64
  int i = idx & 63, l = (idx >> 6) & 2047, kv = idx >> 17;
  if (kv >= NKV) return;
  long base = ((long)kv * L_SEQ + l) * HD + 2 * i;
  bf16x2 x12 = *(bf16x2*)(kb + base);
  float x1 = (float)x12[0], x2 = (float)x12[1];
  float inv = exp2f((float)i * (-NLOG2_10K / 64.0f));
  float s, c; __sincosf((float)l * inv, &s, &c);
  float r1 = x1 * c - x2 * s, r2 = x1 * s + x2 * c;
  bf16x2 o; o[0] = (__bf16)r1; o[1] = (__bf16)r2;
  *(bf16x2*)(kb + base) = o;
  float2 f; f.x = r1; f.y = r2;
#pragma unroll
  for (int rr = 0; rr < 4; ++rr)
    *(float2*)(kout + ((long)(kv * 4 + rr) * L_SEQ + l) * HD + 2 * i) = f;
}

__global__ void v_expand_kernel(const __bf16* __restrict__ vb /*[NKV][L][HD]*/,
                                float* __restrict__ vout /*[NH][L][HD]*/) {
  int idx = blockIdx.x * blockDim.x + threadIdx.x;   // (kv,l,d4): 8*2048*32
  int d4 = idx & 31, l = (idx >> 5) & 2047, kv = idx >> 16;
  if (kv >= NKV) return;
  bf16x4 v = *(const bf16x4*)(vb + ((long)kv * L_SEQ + l) * HD + d4 * 4);
  float4 f; f.x = (float)v[0]; f.y = (float)v[1]; f.z = (float)v[2]; f.w = (float)v[3];
#pragma unroll
  for (int rr = 0; rr < 4; ++rr)
    *(float4*)(vout + ((long)(kv * 4 + rr) * L_SEQ + l) * HD + d4 * 4) = f;
}

// ---------------- V transpose: Vh[NKV][L][HD] -> Vt[NKV][HD][L] ----------------
__global__ void vtrans_kernel(const __bf16* __restrict__ Vh, __bf16* __restrict__ Vt) {
  __shared__ __bf16 tile[64 * 65];
  int kv = blockIdx.z, lb = blockIdx.x * 64, db = blockIdx.y * 64;
  int t = threadIdx.x;
#pragma unroll
  for (int it = 0; it < 2; ++it) {
    int c = it * 256 + t, r = c >> 3, pc = c & 7;
    bf16x8 v = *(const bf16x8*)(Vh + ((long)kv * L_SEQ + lb + r) * HD + db + pc * 8);
#pragma unroll
    for (int e = 0; e < 8; ++e) tile[r * 65 + pc * 8 + e] = v[e];
  }
  __syncthreads();
#pragma unroll
  for (int it = 0; it < 2; ++it) {
    int c = it * 256 + t, r = c >> 3, pc = c & 7;  // r = d row, pc = l chunk
    bf16x8 v;
#pragma unroll
    for (int e = 0; e < 8; ++e) v[e] = tile[(pc * 8 + e) * 65 + r];
    *(bf16x8*)(Vt + ((long)kv * HD + db + r) * L_SEQ + lb + pc * 8) = v;
  }
}

// ---------------- flash attention, S^T formulation ----------------
// Block = (head, 64 q rows), 4 waves x 16 q rows. Per j-tile (64 kv):
//   S^T = K·Q^T  (A=K rows, B=Q regs)  -> lane column = mq, softmax ~in-lane
//   O^T += V^T·P^T (A=Vt rows, B=P rows) -> same lane column = mq
#define PSP 72

__global__ __launch_bounds__(256) void attn2_kernel(
    const __bf16* __restrict__ Q, const __bf16* __restrict__ K,
    const __bf16* __restrict__ Vt, __bf16* __restrict__ O /*[L][NH*HD]*/) {
  __shared__ __bf16 Ks[64 * 128]  __attribute__((aligned(16)));  // [kv][d] swizzled
  __shared__ __bf16 Vts[128 * 64] __attribute__((aligned(16)));  // [d][kv] swizzled
  __shared__ __bf16 Ps[64 * PSP]  __attribute__((aligned(16)));  // [mq][kv]

  const int qb = (int)gridDim.x - 1 - blockIdx.x;   // heavy blocks first
  const int h  = blockIdx.y;
  const int l0 = qb * 64;
  const int t = threadIdx.x, wave = t >> 6, lane = t & 63;
  const int quad = lane >> 4, l16 = lane & 15;
  const int mw = wave * 16;
  const int mq = l0 + mw + l16;          // this lane's q column
  const __bf16* Kh = K  + (long)(h >> 2) * L_SEQ * HD;
  const __bf16* Vh = Vt + (long)(h >> 2) * HD * L_SEQ;

  // Q fragments (B operand): bq[d] = Q[h][mq][d*32 + quad*8 ..+8]
  bf16x8 bq[4];
  {
    const __bf16* qrow = Q + ((long)h * L_SEQ + mq) * HD + quad * 8;
#pragma unroll
    for (int d = 0; d < 4; ++d) bq[d] = *(const bf16x8*)(qrow + d * 32);
  }

  // staging maps (XOR swizzle)
  int kr[4], kk[4], vr[4], vk[4];
#pragma unroll
  for (int it = 0; it < 4; ++it) {
    int c = it * 256 + t;
    kr[it] = c >> 4; kk[it] = ((c & 15) ^ (kr[it] & 7)) * 8;
    vr[it] = c >> 3; vk[it] = ((c & 7)  ^ (vr[it] & 7)) * 8;
  }

  f32x4 o_acc[8] = {};
  float m_run = -1e30f, l_run = 0.f;
  const float SL2 = SCALE * 1.44269504f;   // fold log2(e) -> use exp2

  for (int j = 0; j <= qb; ++j) {
    __syncthreads();
#pragma unroll
    for (int it = 0; it < 4; ++it) {
      gld16(Kh + (long)(j * 64 + kr[it]) * HD + kk[it],
            (char*)Ks + (size_t)(it * 256 + wave * 64) * 16);
      gld16(Vh + (long)vr[it] * L_SEQ + j * 64 + vk[it],
            (char*)Vts + (size_t)(it * 256 + wave * 64) * 16);
    }
    __syncthreads();

    // S^T (64 kv x 16 mq per wave): 16 MFMA
    f32x4 s[4] = {};
#pragma unroll
    for (int dsi = 0; dsi < 4; ++dsi)
#pragma unroll
      for (int tn = 0; tn < 4; ++tn) {
        bf16x8 ak = *(const bf16x8*)((char*)Ks + (tn * 16 + l16) * 256 +
                                     (((dsi * 4 + quad) ^ (l16 & 7)) * 16));
        s[tn] = __builtin_amdgcn_mfma_f32_16x16x32_bf16(ak, bq[dsi], s[tn], 0, 0, 0);
      }

    // scale to log2-units + causal mask (diagonal tile only)
#pragma unroll
    for (int tn = 0; tn < 4; ++tn)
#pragma unroll
      for (int r = 0; r < 4; ++r) {
        float v = s[tn][r] * SL2;
        if (j == qb && (j * 64 + tn * 16 + quad * 4 + r) > mq) v = -3.0e38f;
        s[tn][r] = v;
      }
    // online softmax: 16 in-lane + 2 shuffles (across quads)
    float mx = -3.0e38f;
#pragma unroll
    for (int tn = 0; tn < 4; ++tn)
#pragma unroll
      for (int r = 0; r < 4; ++r) mx = fmaxf(mx, s[tn][r]);
    mx = fmaxf(mx, __shfl_xor(mx, 16, 64));
    mx = fmaxf(mx, __shfl_xor(mx, 32, 64));
    float mnew = fmaxf(m_run, mx);
    float alpha = exp2f(m_run - mnew);
    float rs = 0.f;
#pragma unroll
    for (int tn = 0; tn < 4; ++tn)
#pragma unroll
      for (int r = 0; r < 4; ++r) {
        float p = exp2f(s[tn][r] - mnew);
        s[tn][r] = p; rs += p;
      }
    rs += __shfl_xor(rs, 16, 64);
    rs += __shfl_xor(rs, 32, 64);
    l_run = l_run * alpha + rs;
    m_run = mnew;

    // P^T -> Ps[mq_local][kv]  (per-wave rows; in-order DS, no barrier needed)
#pragma unroll
    for (int tn = 0; tn < 4; ++tn)
#pragma unroll
      for (int r = 0; r < 4; ++r)
        Ps[(mw + l16) * PSP + tn * 16 + quad * 4 + r] = (__bf16)s[tn][r];

    // rescale O, then O^T += V^T·P^T : 16 MFMA
#pragma unroll
    for (int td = 0; td < 8; ++td)
#pragma unroll
      for (int r = 0; r < 4; ++r) o_acc[td][r] *= alpha;
#pragma unroll
    for (int ks = 0; ks < 2; ++ks) {
      bf16x8 bp = *(const bf16x8*)(&Ps[(mw + l16) * PSP + ks * 32 + quad * 8]);
#pragma unroll
      for (int td = 0; td < 8; ++td) {
        bf16x8 av = *(const bf16x8*)((char*)Vts + (td * 16 + l16) * 128 +
                                     (((ks * 4 + quad) ^ (l16 & 7)) * 16));
        o_acc[td] = __builtin_amdgcn_mfma_f32_16x16x32_bf16(av, bp, o_acc[td], 0, 0, 0);
      }
    }
  }

  // epilogue: lane column mq, d = td*16 + quad*4 + r -> 8B packed stores
  float inv_l = 1.0f / l_run;
#pragma unroll
  for (int td = 0; td < 8; ++td) {
    bf16x4 ov;
#pragma unroll
    for (int r = 0; r < 4; ++r) ov[r] = (__bf16)(o_acc[td][r] * inv_l);
    *(bf16x4*)(O + (long)mq * DIM + h * HD + td * 16 + quad * 4) = ov;
  }
}

// ---------------------------------------------------------------------------
extern "C" void kernel_launch(void* const* d_in, const int* in_sizes, int n_in,
                              void* d_out, int out_size, void* d_ws, size_t ws_size,
                              hipStream_t stream) {
  const float* x  = (const float*)d_in[0];
  const float* wq = (const float*)d_in[1];
  const float* wk = (const float*)d_in[2];
  const float* wv = (const float*)d_in[3];
  const float* wo = (const float*)d_in[4];
  // d_in[5] = mask (unused; causal computed in-kernel)

  float* out   = (float*)d_out;                       // 2048*4096
  float* k_out = out + (long)L_SEQ * DIM;             // [32][2048][128]
  float* v_out = k_out + (long)NH * L_SEQ * HD;

  char* ws = (char*)d_ws;
  __bf16* Xb  = (__bf16*)ws; ws += (long)L_SEQ * DIM * 2;
  __bf16* Wqt = (__bf16*)ws; ws += (long)DIM * DIM * 2;          // [N=4096][K=4096]
  __bf16* Wkt = (__bf16*)ws; ws += (long)DIM * (NKV * HD) * 2;   // [1024][4096]
  __bf16* Wvt = (__bf16*)ws; ws += (long)DIM * (NKV * HD) * 2;
  __bf16* Wot = (__bf16*)ws; ws += (long)DIM * DIM * 2;
  __bf16* Qh  = (__bf16*)ws; ws += (long)NH * L_SEQ * HD * 2;    // [32][2048][128]
  __bf16* Kh  = (__bf16*)ws; ws += (long)NKV * L_SEQ * HD * 2;
  __bf16* Vh  = (__bf16*)ws; ws += (long)NKV * L_SEQ * HD * 2;
  __bf16* Vt  = (__bf16*)ws; ws += (long)NKV * HD * L_SEQ * 2;   // [8][128][2048]
  __bf16* Ob  = (__bf16*)ws; ws += (long)L_SEQ * DIM * 2;

  // weight transpose-casts + x cast
  tcast_kernel<<<dim3(DIM / 32, DIM / 32), 256, 0, stream>>>(wq, Wqt, DIM, DIM);
  tcast_kernel<<<dim3((NKV * HD) / 32, DIM / 32), 256, 0, stream>>>(wk, Wkt, DIM, NKV * HD);
  tcast_kernel<<<dim3((NKV * HD) / 32, DIM / 32), 256, 0, stream>>>(wv, Wvt, DIM, NKV * HD);
  tcast_kernel<<<dim3(DIM / 32, DIM / 32), 256, 0, stream>>>(wo, Wot, DIM, DIM);
  {
    long n = (long)L_SEQ * DIM;
    cast_bf16_kernel<<<dim3(n / 1024), 256, 0, stream>>>(x, Xb, n / 4);
  }
  // projections
  gemm128<<<dim3(DIM / 128, L_SEQ / 128, 1), 256, 0, stream>>>(
      Xb, Wqt, Wqt, Qh, Qh, L_SEQ, DIM, DIM, 2);
  gemm128<<<dim3((NKV * HD) / 128, L_SEQ / 128, 2), 256, 0, stream>>>(
      Xb, Wkt, Wvt, Kh, Vh, L_SEQ, NKV * HD, DIM, 2);
  // RoPE + fp32 k/v outputs (GQA-repeated)
  rope_q_kernel<<<dim3((NH * L_SEQ * 64) / 256), 256, 0, stream>>>(Qh);
  rope_k_kernel<<<dim3((NKV * L_SEQ * 64) / 256), 256, 0, stream>>>(Kh, k_out);
  v_expand_kernel<<<dim3((NKV * L_SEQ * 32) / 256), 256, 0, stream>>>(Vh, v_out);
  // V transpose for attention staging
  vtrans_kernel<<<dim3(L_SEQ / 64, HD / 64, NKV), 256, 0, stream>>>(Vh, Vt);
  // flash attention
  attn2_kernel<<<dim3(L_SEQ / 64, NH), 256, 0, stream>>>(Qh, Kh, Vt, Ob);
  // output projection
  gemm128<<<dim3(DIM / 128, L_SEQ / 128, 1), 256, 0, stream>>>(
      Ob, Wot, Wot, out, out, L_SEQ, DIM, DIM, 0);
}

// Round 3
// 617.596 us; speedup vs baseline: 2.5593x; 1.0903x over previous
//
#include <hip/hip_runtime.h>
#include <hip/hip_bf16.h>
#include <math.h>

// ---------------------------------------------------------------------------
// GQA attention fwd. bf16 MFMA everywhere, fp32 accum.
// Round 3: attention load-balance (complementary q-tile pairing -> uniform 33
// chunks/block) + double-buffered K/V staging (prefetch overlaps compute).
// ---------------------------------------------------------------------------

#define L_SEQ 2048
#define DIM   4096
#define NH    32
#define NKV   8
#define HD    128
#define SCALE 0.08838834764831845f   // 128^-0.5

typedef __bf16 bf16x8 __attribute__((ext_vector_type(8)));
typedef __bf16 bf16x4 __attribute__((ext_vector_type(4)));
typedef __bf16 bf16x2 __attribute__((ext_vector_type(2)));
typedef float  f32x4  __attribute__((ext_vector_type(4)));

// async global->LDS, 16B per lane. LDS dst = uniform base + lane*16.
__device__ __forceinline__ void gld16(const void* g, void* l) {
  __builtin_amdgcn_global_load_lds(
      (const __attribute__((address_space(1))) void*)g,
      (__attribute__((address_space(3))) void*)l, 16, 0, 0);
}

// ---------------- plain cast fp32 -> bf16 ----------------
__global__ void cast_bf16_kernel(const float* __restrict__ in,
                                 __bf16* __restrict__ out, long n4) {
  long i = blockIdx.x * (long)blockDim.x + threadIdx.x;
  if (i >= n4) return;
  float4 f = reinterpret_cast<const float4*>(in)[i];
  bf16x4 o;
  o[0] = (__bf16)f.x; o[1] = (__bf16)f.y; o[2] = (__bf16)f.z; o[3] = (__bf16)f.w;
  reinterpret_cast<bf16x4*>(out)[i] = o;
}

// ---------------- transpose-cast: in[K][N] f32 -> out[N][K] bf16 ----------------
// blockIdx.z picks (in0,out0)/(in1,out1) so wk+wv fuse into one launch.
__global__ void tcast_kernel(const float* __restrict__ in0, __bf16* __restrict__ out0,
                             const float* __restrict__ in1, __bf16* __restrict__ out1,
                             int K, int N) {
  __shared__ float tile[32][33];
  const float* in  = blockIdx.z ? in1  : in0;
  __bf16*     out  = blockIdx.z ? out1 : out0;
  int n0 = blockIdx.x * 32, k0 = blockIdx.y * 32;
  int tx = threadIdx.x & 31, ty = threadIdx.x >> 5;   // 256 thr: ty 0..7
#pragma unroll
  for (int i = 0; i < 4; ++i)
    tile[ty + i * 8][tx] = in[(long)(k0 + ty + i * 8) * N + n0 + tx];
  __syncthreads();
#pragma unroll
  for (int i = 0; i < 4; ++i)
    out[(long)(n0 + ty + i * 8) * K + k0 + tx] = (__bf16)tile[tx][ty + i * 8];
}

// ---------------- 128x128 GEMM, C = A[M][K] * Bt[N][K]^T ----------------
// global_load_lds staging, XOR-swizzled chunks (16B), BK=64, 4 waves x 64x64.
// mode 0: fp32 row-major C. mode 2: bf16 head-major C[(col>>7)][row][col&127].
__global__ __launch_bounds__(256) void gemm128(
    const __bf16* __restrict__ A, const __bf16* __restrict__ B0,
    const __bf16* __restrict__ B1, void* __restrict__ C0, void* __restrict__ C1,
    int M, int N, int K, int mode) {
  __shared__ __bf16 As[128 * 64] __attribute__((aligned(16)));
  __shared__ __bf16 Bs[128 * 64] __attribute__((aligned(16)));
  const __bf16* Bt = blockIdx.z ? B1 : B0;
  void* C = blockIdx.z ? C1 : C0;
  const int m0 = blockIdx.y * 128, n0 = blockIdx.x * 128;
  const int t = threadIdx.x, wave = t >> 6, lane = t & 63;
  const int quad = lane >> 4, l16 = lane & 15;
  const int wm = (wave >> 1) * 64, wn = (wave & 1) * 64;

  int ar[4], ak[4];
#pragma unroll
  for (int it = 0; it < 4; ++it) {
    int c = it * 256 + t;
    ar[it] = c >> 3;
    ak[it] = ((c & 7) ^ (ar[it] & 7)) * 8;
  }

  f32x4 acc[4][4] = {};

  for (int kt = 0; kt < K; kt += 64) {
    __syncthreads();
#pragma unroll
    for (int it = 0; it < 4; ++it) {
      gld16(A  + (long)(m0 + ar[it]) * K + kt + ak[it],
            (char*)As + (size_t)(it * 256 + wave * 64) * 16);
      gld16(Bt + (long)(n0 + ar[it]) * K + kt + ak[it],
            (char*)Bs + (size_t)(it * 256 + wave * 64) * 16);
    }
    __syncthreads();
#pragma unroll
    for (int ks = 0; ks < 2; ++ks) {
      bf16x8 af[4], bfr[4];
      const int sw = ((ks * 4 + quad) ^ (l16 & 7)) * 16;
#pragma unroll
      for (int i = 0; i < 4; ++i) {
        af[i]  = *(const bf16x8*)((char*)As + (wm + i * 16 + l16) * 128 + sw);
        bfr[i] = *(const bf16x8*)((char*)Bs + (wn + i * 16 + l16) * 128 + sw);
      }
#pragma unroll
      for (int tm = 0; tm < 4; ++tm)
#pragma unroll
        for (int tn = 0; tn < 4; ++tn)
          acc[tm][tn] = __builtin_amdgcn_mfma_f32_16x16x32_bf16(
              af[tm], bfr[tn], acc[tm][tn], 0, 0, 0);
    }
  }
#pragma unroll
  for (int tm = 0; tm < 4; ++tm)
#pragma unroll
    for (int tn = 0; tn < 4; ++tn)
#pragma unroll
      for (int r = 0; r < 4; ++r) {
        int row = m0 + wm + tm * 16 + quad * 4 + r;
        int col = n0 + wn + tn * 16 + l16;
        float v = acc[tm][tn][r];
        if (mode == 0) {
          ((float*)C)[(long)row * N + col] = v;
        } else {
          long idx = ((long)(col >> 7) * L_SEQ + row) * HD + (col & 127);
          ((__bf16*)C)[idx] = (__bf16)v;
        }
      }
}

// ---------------- RoPE (traditional / interleaved) ----------------
#define NLOG2_10K 13.287712379549449f   // log2(10000)

__global__ void rope_q_kernel(__bf16* __restrict__ q /*[NH][L][HD]*/) {
  int idx = blockIdx.x * blockDim.x + threadIdx.x;   // (h,l,i) : 32*2048*64
  int i = idx & 63, l = (idx >> 6) & 2047, h = idx >> 17;
  if (h >= NH) return;
  long base = ((long)h * L_SEQ + l) * HD + 2 * i;
  bf16x2 x12 = *(bf16x2*)(q + base);
  float x1 = (float)x12[0], x2 = (float)x12[1];
  float inv = exp2f((float)i * (-NLOG2_10K / 64.0f));
  float s, c; __sincosf((float)l * inv, &s, &c);
  bf16x2 o; o[0] = (__bf16)(x1 * c - x2 * s); o[1] = (__bf16)(x1 * s + x2 * c);
  *(bf16x2*)(q + base) = o;
}

// fused: rope K (in-place bf16 + fp32 GQA-repeated out) + V expand (fp32 out)
__global__ void ropekv_kernel(__bf16* __restrict__ kb /*[NKV][L][HD]*/,
                              const __bf16* __restrict__ vb,
                              float* __restrict__ kout /*[NH][L][HD]*/,
                              float* __restrict__ vout) {
  int idx = blockIdx.x * blockDim.x + threadIdx.x;   // (kv,l,i): 8*2048*64
  int i = idx & 63, l = (idx >> 6) & 2047, kv = idx >> 17;
  if (kv >= NKV) return;
  long base = ((long)kv * L_SEQ + l) * HD + 2 * i;
  bf16x2 x12 = *(bf16x2*)(kb + base);
  float x1 = (float)x12[0], x2 = (float)x12[1];
  float inv = exp2f((float)i * (-NLOG2_10K / 64.0f));
  float s, c; __sincosf((float)l * inv, &s, &c);
  float r1 = x1 * c - x2 * s, r2 = x1 * s + x2 * c;
  bf16x2 o; o[0] = (__bf16)r1; o[1] = (__bf16)r2;
  *(bf16x2*)(kb + base) = o;
  float2 kf; kf.x = r1; kf.y = r2;
  bf16x2 vv = *(const bf16x2*)(vb + base);
  float2 vf; vf.x = (float)vv[0]; vf.y = (float)vv[1];
  long off = (long)(kv * 4) * L_SEQ * HD + (long)l * HD + 2 * i;
#pragma unroll
  for (int rr = 0; rr < 4; ++rr) {
    *(float2*)(kout + off) = kf;
    *(float2*)(vout + off) = vf;
    off += (long)L_SEQ * HD;
  }
}

// ---------------- V transpose: Vh[NKV][L][HD] -> Vt[NKV][HD][L] ----------------
__global__ void vtrans_kernel(const __bf16* __restrict__ Vh, __bf16* __restrict__ Vt) {
  __shared__ __bf16 tile[64 * 65];
  int kv = blockIdx.z, lb = blockIdx.x * 64, db = blockIdx.y * 64;
  int t = threadIdx.x;
#pragma unroll
  for (int it = 0; it < 2; ++it) {
    int c = it * 256 + t, r = c >> 3, pc = c & 7;
    bf16x8 v = *(const bf16x8*)(Vh + ((long)kv * L_SEQ + lb + r) * HD + db + pc * 8);
#pragma unroll
    for (int e = 0; e < 8; ++e) tile[r * 65 + pc * 8 + e] = v[e];
  }
  __syncthreads();
#pragma unroll
  for (int it = 0; it < 2; ++it) {
    int c = it * 256 + t, r = c >> 3, pc = c & 7;
    bf16x8 v;
#pragma unroll
    for (int e = 0; e < 8; ++e) v[e] = tile[(pc * 8 + e) * 65 + r];
    *(bf16x8*)(Vt + ((long)kv * HD + db + r) * L_SEQ + lb + pc * 8) = v;
  }
}

// ---------------- flash attention, S^T formulation ----------------
// Block = (pair p, head). Handles q-tiles {p, 31-p} sequentially -> uniform
// 33 kv-chunks per block. Double-buffered K/V staging via global_load_lds.
#define PSP 72

__global__ __launch_bounds__(256) void attn3_kernel(
    const __bf16* __restrict__ Q, const __bf16* __restrict__ K,
    const __bf16* __restrict__ Vt, __bf16* __restrict__ O /*[L][NH*HD]*/) {
  __shared__ __bf16 Ks[2][64 * 128]  __attribute__((aligned(16)));
  __shared__ __bf16 Vts[2][128 * 64] __attribute__((aligned(16)));
  __shared__ __bf16 Ps[64 * PSP]     __attribute__((aligned(16)));

  const int p = blockIdx.x;              // 0..15
  const int h = blockIdx.y;
  const int t = threadIdx.x, wave = t >> 6, lane = t & 63;
  const int quad = lane >> 4, l16 = lane & 15;
  const int mw = wave * 16;
  const __bf16* Kh = K  + (long)(h >> 2) * L_SEQ * HD;
  const __bf16* Vh = Vt + (long)(h >> 2) * HD * L_SEQ;
  const float SL2 = SCALE * 1.44269504f;   // fold log2(e) -> exp2

  // staging maps (XOR swizzle)
  int kr[4], kk[4], vr[4], vk[4];
#pragma unroll
  for (int it = 0; it < 4; ++it) {
    int c = it * 256 + t;
    kr[it] = c >> 4; kk[it] = ((c & 15) ^ (kr[it] & 7)) * 8;
    vr[it] = c >> 3; vk[it] = ((c & 7)  ^ (vr[it] & 7)) * 8;
  }

#pragma unroll 1
  for (int tsel = 0; tsel < 2; ++tsel) {
    const int qb = tsel ? (31 - p) : p;
    const int l0 = qb * 64;
    const int mq = l0 + mw + l16;        // this lane's q column

    // Q fragments (B operand): bq[d] = Q[h][mq][d*32 + quad*8 ..+8]
    bf16x8 bq[4];
    {
      const __bf16* qrow = Q + ((long)h * L_SEQ + mq) * HD + quad * 8;
#pragma unroll
      for (int d = 0; d < 4; ++d) bq[d] = *(const bf16x8*)(qrow + d * 32);
    }

    f32x4 o_acc[8] = {};
    float m_run = -1e30f, l_run = 0.f;

    __syncthreads();   // prior tile's buffer reads done
    // prefetch chunk 0 -> buffer 0
#pragma unroll
    for (int it = 0; it < 4; ++it) {
      gld16(Kh + (long)(0 + kr[it]) * HD + kk[it],
            (char*)Ks[0] + (size_t)(it * 256 + wave * 64) * 16);
      gld16(Vh + (long)vr[it] * L_SEQ + 0 + vk[it],
            (char*)Vts[0] + (size_t)(it * 256 + wave * 64) * 16);
    }

#pragma unroll 1
    for (int j = 0; j <= qb; ++j) {
      const int cur = j & 1;
      __syncthreads();   // drains prefetch j (vmcnt0); buf[cur^1] readers done
      if (j < qb) {
        const int nxt = cur ^ 1;
#pragma unroll
        for (int it = 0; it < 4; ++it) {
          gld16(Kh + (long)((j + 1) * 64 + kr[it]) * HD + kk[it],
                (char*)Ks[nxt] + (size_t)(it * 256 + wave * 64) * 16);
          gld16(Vh + (long)vr[it] * L_SEQ + (j + 1) * 64 + vk[it],
                (char*)Vts[nxt] + (size_t)(it * 256 + wave * 64) * 16);
        }
      }

      // S^T (64 kv x 16 mq per wave): 16 MFMA
      f32x4 s[4] = {};
#pragma unroll
      for (int dsi = 0; dsi < 4; ++dsi)
#pragma unroll
        for (int tn = 0; tn < 4; ++tn) {
          bf16x8 ak = *(const bf16x8*)((char*)Ks[cur] + (tn * 16 + l16) * 256 +
                                       (((dsi * 4 + quad) ^ (l16 & 7)) * 16));
          s[tn] = __builtin_amdgcn_mfma_f32_16x16x32_bf16(ak, bq[dsi], s[tn], 0, 0, 0);
        }

      // scale (log2 units) + causal mask (diagonal tile only)
#pragma unroll
      for (int tn = 0; tn < 4; ++tn)
#pragma unroll
        for (int r = 0; r < 4; ++r) {
          float v = s[tn][r] * SL2;
          if (j == qb && (j * 64 + tn * 16 + quad * 4 + r) > mq) v = -3.0e38f;
          s[tn][r] = v;
        }
      // online softmax: 16 in-lane + 2 shuffles
      float mx = -3.0e38f;
#pragma unroll
      for (int tn = 0; tn < 4; ++tn)
#pragma unroll
        for (int r = 0; r < 4; ++r) mx = fmaxf(mx, s[tn][r]);
      mx = fmaxf(mx, __shfl_xor(mx, 16, 64));
      mx = fmaxf(mx, __shfl_xor(mx, 32, 64));
      float mnew = fmaxf(m_run, mx);
      float alpha = exp2f(m_run - mnew);
      float rs = 0.f;
#pragma unroll
      for (int tn = 0; tn < 4; ++tn)
#pragma unroll
        for (int r = 0; r < 4; ++r) {
          float pe = exp2f(s[tn][r] - mnew);
          s[tn][r] = pe; rs += pe;
        }
      rs += __shfl_xor(rs, 16, 64);
      rs += __shfl_xor(rs, 32, 64);
      l_run = l_run * alpha + rs;
      m_run = mnew;

      // P^T -> Ps[mq_local][kv], packed 8B stores (r=0..3 are consecutive kv)
#pragma unroll
      for (int tn = 0; tn < 4; ++tn) {
        bf16x4 pv;
#pragma unroll
        for (int r = 0; r < 4; ++r) pv[r] = (__bf16)s[tn][r];
        *(bf16x4*)(&Ps[(mw + l16) * PSP + tn * 16 + quad * 4]) = pv;
      }

      // rescale O, then O^T += V^T·P^T : 16 MFMA
#pragma unroll
      for (int td = 0; td < 8; ++td)
#pragma unroll
        for (int r = 0; r < 4; ++r) o_acc[td][r] *= alpha;
#pragma unroll
      for (int ks = 0; ks < 2; ++ks) {
        bf16x8 bp = *(const bf16x8*)(&Ps[(mw + l16) * PSP + ks * 32 + quad * 8]);
#pragma unroll
        for (int td = 0; td < 8; ++td) {
          bf16x8 av = *(const bf16x8*)((char*)Vts[cur] + (td * 16 + l16) * 128 +
                                       (((ks * 4 + quad) ^ (l16 & 7)) * 16));
          o_acc[td] = __builtin_amdgcn_mfma_f32_16x16x32_bf16(av, bp, o_acc[td], 0, 0, 0);
        }
      }
    }

    // epilogue: lane column mq, d = td*16 + quad*4 + r -> 8B packed stores
    float inv_l = 1.0f / l_run;
#pragma unroll
    for (int td = 0; td < 8; ++td) {
      bf16x4 ov;
#pragma unroll
      for (int r = 0; r < 4; ++r) ov[r] = (__bf16)(o_acc[td][r] * inv_l);
      *(bf16x4*)(O + (long)mq * DIM + h * HD + td * 16 + quad * 4) = ov;
    }
  }
}

// ---------------------------------------------------------------------------
extern "C" void kernel_launch(void* const* d_in, const int* in_sizes, int n_in,
                              void* d_out, int out_size, void* d_ws, size_t ws_size,
                              hipStream_t stream) {
  const float* x  = (const float*)d_in[0];
  const float* wq = (const float*)d_in[1];
  const float* wk = (const float*)d_in[2];
  const float* wv = (const float*)d_in[3];
  const float* wo = (const float*)d_in[4];

  float* out   = (float*)d_out;                       // 2048*4096
  float* k_out = out + (long)L_SEQ * DIM;             // [32][2048][128]
  float* v_out = k_out + (long)NH * L_SEQ * HD;

  char* ws = (char*)d_ws;
  __bf16* Xb  = (__bf16*)ws; ws += (long)L_SEQ * DIM * 2;
  __bf16* Wqt = (__bf16*)ws; ws += (long)DIM * DIM * 2;          // [N][K]
  __bf16* Wkt = (__bf16*)ws; ws += (long)DIM * (NKV * HD) * 2;
  __bf16* Wvt = (__bf16*)ws; ws += (long)DIM * (NKV * HD) * 2;
  __bf16* Wot = (__bf16*)ws; ws += (long)DIM * DIM * 2;
  __bf16* Qh  = (__bf16*)ws; ws += (long)NH * L_SEQ * HD * 2;    // [32][2048][128]
  __bf16* Kh  = (__bf16*)ws; ws += (long)NKV * L_SEQ * HD * 2;
  __bf16* Vh  = (__bf16*)ws; ws += (long)NKV * L_SEQ * HD * 2;
  __bf16* Vt  = (__bf16*)ws; ws += (long)NKV * HD * L_SEQ * 2;   // [8][128][2048]
  __bf16* Ob  = (__bf16*)ws; ws += (long)L_SEQ * DIM * 2;

  // weight transpose-casts + x cast
  tcast_kernel<<<dim3(DIM / 32, DIM / 32, 1), 256, 0, stream>>>(wq, Wqt, wq, Wqt, DIM, DIM);
  tcast_kernel<<<dim3((NKV * HD) / 32, DIM / 32, 2), 256, 0, stream>>>(wk, Wkt, wv, Wvt, DIM, NKV * HD);
  tcast_kernel<<<dim3(DIM / 32, DIM / 32, 1), 256, 0, stream>>>(wo, Wot, wo, Wot, DIM, DIM);
  {
    long n = (long)L_SEQ * DIM;
    cast_bf16_kernel<<<dim3(n / 1024), 256, 0, stream>>>(x, Xb, n / 4);
  }
  // projections
  gemm128<<<dim3(DIM / 128, L_SEQ / 128, 1), 256, 0, stream>>>(
      Xb, Wqt, Wqt, Qh, Qh, L_SEQ, DIM, DIM, 2);
  gemm128<<<dim3((NKV * HD) / 128, L_SEQ / 128, 2), 256, 0, stream>>>(
      Xb, Wkt, Wvt, Kh, Vh, L_SEQ, NKV * HD, DIM, 2);
  // RoPE + fp32 k/v outputs (GQA-repeated), fused
  rope_q_kernel<<<dim3((NH * L_SEQ * 64) / 256), 256, 0, stream>>>(Qh);
  ropekv_kernel<<<dim3((NKV * L_SEQ * 64) / 256), 256, 0, stream>>>(Kh, Vh, k_out, v_out);
  // V transpose for attention staging
  vtrans_kernel<<<dim3(L_SEQ / 64, HD / 64, NKV), 256, 0, stream>>>(Vh, Vt);
  // flash attention (paired q-tiles, double-buffered staging)
  attn3_kernel<<<dim3(16, NH), 256, 0, stream>>>(Qh, Kh, Vt, Ob);
  // output projection
  gemm128<<<dim3(DIM / 128, L_SEQ / 128, 1), 256, 0, stream>>>(
      Ob, Wot, Wot, out, out, L_SEQ, DIM, DIM, 0);
}